// Round 12
// baseline (235.631 us; speedup 1.0000x reference)
//
#include <hip/hip_runtime.h>

#define B 256
#define KDIM 8
#define IDIM 1152
#define CDIM 10
#define CO 160
#define IK 9216        // IDIM*KDIM
#define NBLK 256
#define NTHR 512

typedef __bf16 bf16x8 __attribute__((ext_vector_type(8)));
typedef unsigned short ushort8 __attribute__((ext_vector_type(8)));
typedef float f32x4 __attribute__((ext_vector_type(4)));

__device__ __forceinline__ unsigned short f2bf(float f) {
  unsigned u = __float_as_uint(f);
  unsigned r = u + 0x7fff + ((u >> 16) & 1);   // RNE
  return (unsigned short)(r >> 16);
}

union U8B8 { ushort8 u; bf16x8 h; };
union U8U64 { ushort8 s; bf16x8 h; unsigned long long u[2]; };

// ---- LLC-coherent (agent-scope, cache-bypassing) accessors ----------------
__device__ __forceinline__ void st64_llc(void* p, unsigned long long v) {
  __hip_atomic_store((unsigned long long*)p, v, __ATOMIC_RELAXED,
                     __HIP_MEMORY_SCOPE_AGENT);
}
__device__ __forceinline__ unsigned long long ld64_llc(const void* p) {
  return __hip_atomic_load((unsigned long long*)p, __ATOMIC_RELAXED,
                           __HIP_MEMORY_SCOPE_AGENT);
}
__device__ __forceinline__ void st32_llc(void* p, unsigned v) {
  __hip_atomic_store((unsigned*)p, v, __ATOMIC_RELAXED,
                     __HIP_MEMORY_SCOPE_AGENT);
}
__device__ __forceinline__ float ldf_llc(const float* p) {
  return __hip_atomic_load((float*)p, __ATOMIC_RELAXED,
                           __HIP_MEMORY_SCOPE_AGENT);
}

// Fence-free grid barrier. Arrive = one device-scope RMW; poll = agent-scope
// LOAD (reads to one LLC line are served concurrently — unlike RMW polls,
// which serialize and cost ~18us/barrier, the round-11 lesson).
__device__ __forceinline__ void gbar(int* cnt, int& ep) {
  __syncthreads();
  ep += NBLK;
  if (threadIdx.x == 0) {
    atomicAdd(cnt, 1);
    int g = 0;
    while (__hip_atomic_load(cnt, __ATOMIC_RELAXED,
                             __HIP_MEMORY_SCOPE_AGENT) < ep) {
      __builtin_amdgcn_s_sleep(4);
      if (++g > 8000000) break;                  // bailout: wrong, not hung
    }
  }
  __syncthreads();
}

// Fenced barrier (after prep only): publishes plain-stored xtbT/xtkb/logits.
__device__ __forceinline__ void gbar_fence(int* cnt, int& ep) {
  __syncthreads();
  ep += NBLK;
  if (threadIdx.x == 0) {
    __threadfence();
    atomicAdd(cnt, 1);
    int g = 0;
    while (__hip_atomic_load(cnt, __ATOMIC_RELAXED,
                             __HIP_MEMORY_SCOPE_AGENT) < ep) {
      __builtin_amdgcn_s_sleep(4);
      if (++g > 8000000) break;
    }
    __threadfence();
  }
  __syncthreads();
}

// ---------------------------------------------------------------------------
// Persistent kernel: 256 blocks x 512 threads (8 waves; 2/SIMD; 1 block/CU).
// P -> fenced bar; iter: S -> SQ -> AGR -> Q (fence-free bars).
// Cross-phase data via sc1; immutable inputs (x, W) and prep outputs
// (xtbT, xtkb) via normal cached loads.
// ---------------------------------------------------------------------------
template <int NP>
__global__ void __launch_bounds__(NTHR)
caps_all(const float* __restrict__ x, const float* __restrict__ W,
         float* __restrict__ out, int* __restrict__ bar,
         float* __restrict__ logits, float* __restrict__ qT,
         float* __restrict__ s_part, unsigned short* __restrict__ xtbT,
         unsigned short* __restrict__ xtkb, unsigned short* __restrict__ outT) {
  __shared__ __align__(16) unsigned char smem[82944];
  const int gid = blockIdx.x;
  const int t = threadIdx.x;
  const int w8 = t >> 6, l = t & 63;
  const int lr = l & 15, lq = l >> 4;
  const int gwid = gid * 8 + w8;           // 0..2047
  int ep = 0;

  // ================= Phase P: prep =================
  for (int job = gid; job < 288; job += NBLK) {
    float* tf = (float*)smem;              // tile[k][bb][ii]: k*1056+bb*33+ii
    const int i0 = (job % 36) * 32;
    const int b0 = (job / 36) * 32;
    const int tx = t & 31, ty = t >> 5;    // ty 0..15
#pragma unroll
    for (int r = 0; r < 2; ++r) {
      int b = b0 + ty + r * 16;
#pragma unroll
      for (int k = 0; k < 8; ++k)
        tf[k * 1056 + (ty + r * 16) * 33 + tx] =
            x[((size_t)b * KDIM + k) * IDIM + i0 + tx];
    }
    __syncthreads();
    // xtbT[b][i*8+k]
#pragma unroll
    for (int r = 0; r < 2; ++r) {
      int idx = r * 512 + t;
      int bb = idx >> 5, ii = idx & 31;
      ushort8 v;
#pragma unroll
      for (int k = 0; k < 8; ++k) v[k] = f2bf(tf[k * 1056 + bb * 33 + ii]);
      *reinterpret_cast<ushort8*>(&xtbT[(size_t)(b0 + bb) * IK + (i0 + ii) * 8]) = v;
    }
    // xtkb[(i*8+k)][b]
    {
      const int k = ty & 7, half = ty >> 3;
#pragma unroll
      for (int r = 0; r < 16; ++r) {
        int ii = half * 16 + r;
        xtkb[((size_t)(i0 + ii) * 8 + k) * B + b0 + tx] =
            f2bf(tf[k * 1056 + tx * 33 + ii]);
      }
    }
    __syncthreads();
  }
  if (gid < 10)
    for (int i = t; i < IDIM; i += NTHR)
      st32_llc(&qT[gid * IDIM + i], __float_as_uint(1.f / (float)IDIM));
  if (gid < 23) {
    int idx = gid * NTHR + t;
    if (idx < IDIM * CDIM) logits[idx] = 0.f;
  }
  gbar_fence(bar, ep);

  for (int it = 0; it < 3; ++it) {
    // ================= Phase S: split-K MFMA s-GEMM =================
    {
      constexpr int KSPAN = IK / NP;       // 288 at NP=32
      constexpr int CHUNKS = KSPAN / 32;   // 9
      constexpr int ISPAN = KSPAN / 8;     // 36 i's per split
      for (int job = gwid; job < 160 * NP; job += 2048) {
        const int bt = job & 15;
        const int cc = (job >> 4) % 10;
        const int g = job / 160;
        const unsigned short* Bp =
            &xtbT[(size_t)(bt * 16 + lr) * IK + g * KSPAN + lq * 8];
        const float* qp = &qT[cc * IDIM + g * ISPAN + lq];
        // batch-issue all q loads (independent -> one LLC latency)
        float qv[CHUNKS];
#pragma unroll
        for (int t9 = 0; t9 < CHUNKS; ++t9) qv[t9] = ldf_llc(qp + t9 * 4);
        f32x4 acc = (f32x4){0.f, 0.f, 0.f, 0.f};
#pragma unroll
        for (int t9 = 0; t9 < CHUNKS; ++t9) {
          const int i = g * ISPAN + t9 * 4 + lq;
          const float* wsrc = &W[((size_t)i * CDIM + cc) * 128 + lr * 8];
          float4 w0 = *(const float4*)wsrc;
          float4 w1 = *(const float4*)(wsrc + 4);
          U8B8 a;
          a.u[0] = f2bf(w0.x * qv[t9]); a.u[1] = f2bf(w0.y * qv[t9]);
          a.u[2] = f2bf(w0.z * qv[t9]); a.u[3] = f2bf(w0.w * qv[t9]);
          a.u[4] = f2bf(w1.x * qv[t9]); a.u[5] = f2bf(w1.y * qv[t9]);
          a.u[6] = f2bf(w1.z * qv[t9]); a.u[7] = f2bf(w1.w * qv[t9]);
          U8B8 bb;
          bb.u = *reinterpret_cast<const ushort8*>(Bp + t9 * 32);  // cached
          acc = __builtin_amdgcn_mfma_f32_16x16x32_bf16(a.h, bb.h, acc, 0, 0, 0);
        }
        union { f32x4 f; unsigned long long u[2]; } cv;
        cv.f = acc;
        float* dp = &s_part[((size_t)g * B + bt * 16 + lr) * CO + cc * 16 + lq * 4];
        st64_llc(dp, cv.u[0]);
        st64_llc(dp + 2, cv.u[1]);
      }
    }
    gbar(bar, ep);

    // ================= Phase SQ: reduce + squash (2 b per block) ===========
    {
      float* sq = (float*)smem;      // [2][160], then reused for squashed vals
      float* fo = sq + 320;          // [2][16]
      if (gid < 128) {
        const int b0 = gid * 2;
        const int bi = t / 160, tt = t % 160;
        float vv = 0.f;
        if (t < 320) {
#pragma unroll
          for (int g = 0; g < NP; ++g)          // full unroll: NP loads in flight
            vv += ldf_llc(&s_part[((size_t)g * B + b0 + bi) * CO + tt]);
          sq[bi * 160 + tt] = vv * vv;
        }
        __syncthreads();
        if (t < 32) {
          int bj = t >> 4, o = t & 15;
          float ns = 0.f;
#pragma unroll
          for (int c = 0; c < CDIM; ++c) ns += sq[bj * 160 + c * 16 + o];
          fo[bj * 16 + o] = (ns / (1.f + ns)) / (sqrtf(ns) + 1e-10f);
        }
        __syncthreads();
        if (t < 320) {
          float v = vv * fo[bi * 16 + (tt & 15)];
          if (it == 2) out[(size_t)(b0 + bi) * CO + tt] = v;
          else         sq[bi * 160 + tt] = v;
        }
        if (it != 2) {
          __syncthreads();
          if (t < 160) {
            unsigned u = (unsigned)f2bf(sq[t]) | ((unsigned)f2bf(sq[160 + t]) << 16);
            st32_llc(&outT[(size_t)t * B + b0], u);
          }
        }
      }
    }
    if (it == 2) break;
    gbar(bar, ep);

    // ================= Phase AGR: MFMA y-GEMM + W-contract =================
    {
      float* yl = (float*)smem;      // [128][161] f32 = 82.4 KB
      for (int job = gid; job < 288; job += NBLK) {
        const int bx = job % 72, bh = job / 72;
        __syncthreads();             // protect yl reuse across jobs
        f32x4 acc[10];
#pragma unroll
        for (int nt = 0; nt < 10; ++nt) acc[nt] = (f32x4){0.f, 0.f, 0.f, 0.f};
        const unsigned short* Ap =
            &xtkb[(size_t)(bx * 128 + w8 * 16 + lr) * B + bh * 64 + lq * 8];
        const unsigned short* Bp = &outT[(size_t)lr * B + bh * 64 + lq * 8];
#pragma unroll
        for (int kc = 0; kc < 2; ++kc) {
          U8B8 a;
          a.u = *reinterpret_cast<const ushort8*>(Ap + kc * 32);  // cached
#pragma unroll
          for (int nt = 0; nt < 10; ++nt) {
            U8U64 bv;
            bv.u[0] = ld64_llc(Bp + (size_t)nt * 16 * B + kc * 32);
            bv.u[1] = ld64_llc(Bp + (size_t)nt * 16 * B + kc * 32 + 4);
            acc[nt] = __builtin_amdgcn_mfma_f32_16x16x32_bf16(a.h, bv.h, acc[nt], 0, 0, 0);
          }
        }
#pragma unroll
        for (int nt = 0; nt < 10; ++nt)
#pragma unroll
          for (int j = 0; j < 4; ++j)
            yl[(w8 * 16 + lq * 4 + j) * 161 + nt * 16 + lr] = acc[nt][j];
        __syncthreads();
        if (t < 320) {
          const int ii = t / 20, rem = t % 20, ccl = rem >> 1, oh = rem & 1;
          const float* Wp = &W[((size_t)(bx * 16 + ii) * CDIM + ccl) * 128 + oh * 64];
          float sum = 0.f;
#pragma unroll
          for (int o = 0; o < 8; ++o) {
            float4 w0 = *(const float4*)(&Wp[o * 8]);
            float4 w1 = *(const float4*)(&Wp[o * 8 + 4]);
            int co = ccl * 16 + oh * 8 + o;
            sum += w0.x * yl[(ii * 8 + 0) * 161 + co] + w0.y * yl[(ii * 8 + 1) * 161 + co]
                 + w0.z * yl[(ii * 8 + 2) * 161 + co] + w0.w * yl[(ii * 8 + 3) * 161 + co]
                 + w1.x * yl[(ii * 8 + 4) * 161 + co] + w1.y * yl[(ii * 8 + 5) * 161 + co]
                 + w1.z * yl[(ii * 8 + 6) * 161 + co] + w1.w * yl[(ii * 8 + 7) * 161 + co];
          }
          sum += __shfl_xor(sum, 1);
          if (oh == 0)
            atomicAdd(&logits[(bx * 16 + ii) * CDIM + ccl], sum * (1.f / (float)B));
        }
      }
    }
    gbar(bar, ep);

    // ================= Phase Q: softmax -> qT =================
    if (gid < 10) {
      const int c = gid;
      float* cls = (float*)smem;     // [1152]
      float* red8 = cls + IDIM;      // [8]
      float m = -1e30f;
      for (int i = t; i < IDIM; i += NTHR) {
        float v = ldf_llc(&logits[i * CDIM + c]);
        cls[i] = v;
        m = fmaxf(m, v);
      }
#pragma unroll
      for (int off = 32; off; off >>= 1) m = fmaxf(m, __shfl_xor(m, off));
      if ((t & 63) == 0) red8[t >> 6] = m;
      __syncthreads();
#pragma unroll
      for (int r = 0; r < 8; ++r) m = fmaxf(m, red8[r]);
      __syncthreads();
      float ps = 0.f;
      for (int i = t; i < IDIM; i += NTHR) {
        float e = expf(cls[i] - m);
        cls[i] = e;
        ps += e;
      }
#pragma unroll
      for (int off = 32; off; off >>= 1) ps += __shfl_xor(ps, off);
      if ((t & 63) == 0) red8[t >> 6] = ps;
      __syncthreads();
      float tot = 0.f;
#pragma unroll
      for (int r = 0; r < 8; ++r) tot += red8[r];
      const float rinv = 1.f / tot;
      for (int i = t; i < IDIM; i += NTHR)
        st32_llc(&qT[c * IDIM + i], __float_as_uint(cls[i] * rinv));
    }
    gbar(bar, ep);
  }
}

// ---------------------------------------------------------------------------
extern "C" void kernel_launch(void* const* d_in, const int* in_sizes, int n_in,
                              void* d_out, int out_size, void* d_ws, size_t ws_size,
                              hipStream_t stream) {
  const float* x = (const float*)d_in[0];       // [B,K,I] f32
  const float* W = (const float*)d_in[1];       // [I,C,O,K] f32
  float* out = (float*)d_out;                   // [B,C,O,1] f32

  const size_t fixed = 16 + (size_t)(IDIM * CDIM) * 8 +
                       ((size_t)B * IK + (size_t)IK * B + (size_t)CO * B) * 2;
  const int np = (ws_size >= fixed + 32ull * B * CO * 4) ? 32 : 8;

  int* bar       = (int*)d_ws;                               // 16 B
  float* logits  = (float*)((char*)d_ws + 16);               // I*C f32
  float* qT      = logits + IDIM * CDIM;                     // C*I f32
  float* s_part  = qT + IDIM * CDIM;                         // np*B*CO f32
  unsigned short* xtbT = (unsigned short*)(s_part + (size_t)np * B * CO);
  unsigned short* xtkb = xtbT + (size_t)B * IK;
  unsigned short* outT = xtkb + (size_t)IK * B;

  hipMemsetAsync(bar, 0, 16, stream);
  if (np == 32)
    caps_all<32><<<NBLK, NTHR, 0, stream>>>(x, W, out, bar, logits, qT,
                                            s_part, xtbT, xtkb, outT);
  else
    caps_all<8><<<NBLK, NTHR, 0, stream>>>(x, W, out, bar, logits, qT,
                                           s_part, xtbT, xtkb, outT);
}

// Round 13
// 110.795 us; speedup vs baseline: 2.1267x; 2.1267x over previous
//
#include <hip/hip_runtime.h>

#define B 256
#define KDIM 8
#define IDIM 1152
#define CDIM 10
#define CO 160
#define IK 9216        // IDIM*KDIM
#define NPART 8        // split-K partials in k_s
#define SUBW 8

typedef __bf16 bf16x8 __attribute__((ext_vector_type(8)));
typedef unsigned short ushort8 __attribute__((ext_vector_type(8)));
typedef float f32x4 __attribute__((ext_vector_type(4)));

__device__ __forceinline__ unsigned short f2bf(float f) {
  unsigned u = __float_as_uint(f);
  unsigned r = u + 0x7fff + ((u >> 16) & 1);   // RNE
  return (unsigned short)(r >> 16);
}

union U8B8 { ushort8 u; bf16x8 h; };

// ---------------------------------------------------------------------------
// Kernel 1 (prep): role A (blocks 0..287): x -> xtbT bf16 [b][i*8+k] AND
// xtkb bf16 [i*8+k][b] (one x read). role B (288..359): W -> Wrb bf16
// [c*16+o][i*8+k] (UNSCALED); first 45 role-B blocks zero logits.
// ---------------------------------------------------------------------------
__global__ void __launch_bounds__(256) k_prep(const float* __restrict__ x,
                                              const float* __restrict__ W,
                                              unsigned short* __restrict__ xtbT,
                                              unsigned short* __restrict__ xtkb,
                                              unsigned short* __restrict__ Wrb,
                                              float* __restrict__ logits) {
  __shared__ __align__(16) unsigned char smem[41280];
  const int bid = blockIdx.x;
  const int t = threadIdx.x;
  if (bid < 288) {
    float* tf = (float*)smem;                 // tile[k][bb][ii]: k*1056+bb*33+ii
    const int i0 = (bid % 36) * 32;
    const int b0 = (bid / 36) * 32;
    const int tx = t & 31, ty = t >> 5;       // ty 0..7
#pragma unroll
    for (int r = 0; r < 4; ++r) {
      int b = b0 + ty + r * 8;
#pragma unroll
      for (int k = 0; k < 8; ++k)
        tf[k * 1056 + (ty + r * 8) * 33 + tx] =
            x[((size_t)b * KDIM + k) * IDIM + i0 + tx];
    }
    __syncthreads();
    // xtbT[b][i*8+k]  (ushort8 per (b,i))
#pragma unroll
    for (int r = 0; r < 4; ++r) {
      int idx = r * 256 + t;
      int bb = idx >> 5, ii = idx & 31;
      ushort8 v;
#pragma unroll
      for (int k = 0; k < 8; ++k) v[k] = f2bf(tf[k * 1056 + bb * 33 + ii]);
      *reinterpret_cast<ushort8*>(&xtbT[(size_t)(b0 + bb) * IK + (i0 + ii) * 8]) = v;
    }
    // xtkb[(i*8+k)][b]  (ty = k, tx = b-lane)
#pragma unroll
    for (int ii = 0; ii < 32; ++ii)
      xtkb[((size_t)(i0 + ii) * 8 + ty) * B + b0 + tx] =
          f2bf(tf[ty * 1056 + tx * 33 + ii]);
  } else {
    unsigned short* wt = (unsigned short*)smem;  // wt[ii][j], row stride 1288
    const int bz = bid - 288;                    // 0..71
    const int i0 = bz * 16;
#pragma unroll
    for (int ii = 0; ii < 16; ++ii) {
      const float* src = &W[(size_t)(i0 + ii) * 1280];
#pragma unroll
      for (int p = 0; p < 5; ++p) {
        int j = p * 256 + t;
        wt[ii * 1288 + j] = f2bf(src[j]);        // unscaled
      }
    }
    __syncthreads();
#pragma unroll
    for (int p = 0; p < 10; ++p) {
      int idx = p * 256 + t;
      int co = idx >> 4, ii = idx & 15;
      ushort8 v = *reinterpret_cast<const ushort8*>(&wt[ii * 1288 + co * 8]);
      *reinterpret_cast<ushort8*>(&Wrb[(size_t)co * IK + (i0 + ii) * 8]) = v;
    }
    if (bz < 45) logits[bz * 256 + t] = 0.f;
  }
}

// ---------------------------------------------------------------------------
// Kernel 2 (k_s, round-5 proven): fused per-class softmax + MFMA split-K.
// s[o,b] = sum_ik (q[c,i]*Wrb[c*16+o][ik]) * xtbT[b][ik]
// grid (10 c, 4 bt4, 8 g), block 256 = 4 waves; wave split s = g*4+w, 9 chunks.
// ---------------------------------------------------------------------------
__global__ void __launch_bounds__(256) k_s(const float* __restrict__ logits,
                                           const unsigned short* __restrict__ Wrb,
                                           const unsigned short* __restrict__ xtbT,
                                           float* __restrict__ s_part) {
  const int c = blockIdx.x, bt4 = blockIdx.y, g = blockIdx.z;
  const int t = threadIdx.x, w = t >> 6, l = t & 63;
  const int lr = l & 15, lq = l >> 4;
  const int s = g * 4 + w;

  __shared__ float cls[IDIM];
  __shared__ float red4[4];
  __shared__ float red[3 * 1088];

  // ---- softmax over i for class c (redundant per block; cheap) ----
  float m = -1e30f;
  for (int i = t; i < IDIM; i += 256) {
    float v = logits[i * CDIM + c];
    cls[i] = v;
    m = fmaxf(m, v);
  }
#pragma unroll
  for (int off = 32; off; off >>= 1) m = fmaxf(m, __shfl_xor(m, off));
  if ((t & 63) == 0) red4[t >> 6] = m;
  __syncthreads();
  m = fmaxf(fmaxf(red4[0], red4[1]), fmaxf(red4[2], red4[3]));
  __syncthreads();
  float ps = 0.f;
  for (int i = t; i < IDIM; i += 256) {
    float e = expf(cls[i] - m);
    cls[i] = e;
    ps += e;
  }
#pragma unroll
  for (int off = 32; off; off >>= 1) ps += __shfl_xor(ps, off);
  if ((t & 63) == 0) red4[t >> 6] = ps;
  __syncthreads();
  const float rinv = 1.f / (red4[0] + red4[1] + red4[2] + red4[3]);
  for (int i = t; i < IDIM; i += 256) cls[i] *= rinv;
  __syncthreads();

  // ---- MFMA main loop ----
  f32x4 acc[4];
#pragma unroll
  for (int j = 0; j < 4; ++j) acc[j] = (f32x4){0.f, 0.f, 0.f, 0.f};

  const unsigned short* Ap  = &Wrb[((size_t)c * 16 + lr) * IK + lq * 8];
  const unsigned short* Bp0 = &xtbT[((size_t)(bt4 * 64 +  0 + lr)) * IK + lq * 8];
  const unsigned short* Bp1 = &xtbT[((size_t)(bt4 * 64 + 16 + lr)) * IK + lq * 8];
  const unsigned short* Bp2 = &xtbT[((size_t)(bt4 * 64 + 32 + lr)) * IK + lq * 8];
  const unsigned short* Bp3 = &xtbT[((size_t)(bt4 * 64 + 48 + lr)) * IK + lq * 8];

#pragma unroll 3
  for (int t9 = 0; t9 < 9; ++t9) {
    const int kc = s * 9 + t9;
    const int off = kc * 32;
    ushort8 av = *reinterpret_cast<const ushort8*>(Ap + off);
    float qv = cls[kc * 4 + lq];
    U8B8 b0; b0.u = *reinterpret_cast<const ushort8*>(Bp0 + off);
    U8B8 b1; b1.u = *reinterpret_cast<const ushort8*>(Bp1 + off);
    U8B8 b2; b2.u = *reinterpret_cast<const ushort8*>(Bp2 + off);
    U8B8 b3; b3.u = *reinterpret_cast<const ushort8*>(Bp3 + off);
    U8B8 a;
#pragma unroll
    for (int e = 0; e < 8; ++e) {
      float f = __uint_as_float((unsigned)av[e] << 16) * qv;
      a.u[e] = f2bf(f);
    }
    acc[0] = __builtin_amdgcn_mfma_f32_16x16x32_bf16(a.h, b0.h, acc[0], 0, 0, 0);
    acc[1] = __builtin_amdgcn_mfma_f32_16x16x32_bf16(a.h, b1.h, acc[1], 0, 0, 0);
    acc[2] = __builtin_amdgcn_mfma_f32_16x16x32_bf16(a.h, b2.h, acc[2], 0, 0, 0);
    acc[3] = __builtin_amdgcn_mfma_f32_16x16x32_bf16(a.h, b3.h, acc[3], 0, 0, 0);
  }

  // ---- cross-wave reduce, store by wave 0 ----
  if (w) {
#pragma unroll
    for (int j = 0; j < 4; ++j)
#pragma unroll
      for (int j2 = 0; j2 < 4; ++j2)
        red[(w - 1) * 1088 + l * 17 + j * 4 + j2] = acc[j][j2];
  }
  __syncthreads();
  if (w == 0) {
#pragma unroll
    for (int r = 0; r < 3; ++r)
#pragma unroll
      for (int j = 0; j < 4; ++j)
#pragma unroll
        for (int j2 = 0; j2 < 4; ++j2)
          acc[j][j2] += red[r * 1088 + l * 17 + j * 4 + j2];
#pragma unroll
    for (int j = 0; j < 4; ++j)
#pragma unroll
      for (int j2 = 0; j2 < 4; ++j2)
        s_part[((size_t)g * B + bt4 * 64 + j * 16 + lr) * CO + c * 16 + lq * 4 + j2] =
            acc[j][j2];
  }
}

// ---------------------------------------------------------------------------
// Kernel 3 (k_sqm, round-7 proven): reduce split-K partials + squash ->
// outT bf16 [co][b]. grid 16, block 256: lane = b (coalesced), t>>4 = o.
// ---------------------------------------------------------------------------
__global__ void __launch_bounds__(256) k_sqm(const float* __restrict__ s_part,
                                             unsigned short* __restrict__ outT) {
  const int t = threadIdx.x;
  const int b = blockIdx.x * 16 + (t & 15);
  const int o = t >> 4;
  float v[CDIM];
  float ns = 0.f;
#pragma unroll
  for (int c = 0; c < CDIM; ++c) {
    float sv = 0.f;
#pragma unroll
    for (int p = 0; p < NPART; ++p)
      sv += s_part[((size_t)p * B + b) * CO + c * 16 + o];
    v[c] = sv;
    ns += sv * sv;
  }
  float f = (ns / (1.f + ns)) / (sqrtf(ns) + 1e-10f);
#pragma unroll
  for (int c = 0; c < CDIM; ++c)
    outT[(c * 16 + o) * B + b] = f2bf(v[c] * f);
}

// ---------------------------------------------------------------------------
// Kernel 4 (k_sqf, last iter): reduce + squash -> d_out f32 [b][c][o].
// ---------------------------------------------------------------------------
__global__ void __launch_bounds__(256) k_sqf(const float* __restrict__ s_part,
                                             float* __restrict__ out) {
  int idx = blockIdx.x * 256 + threadIdx.x;
  int b = idx >> 4, o = idx & 15;
  float v[CDIM];
#pragma unroll
  for (int c = 0; c < CDIM; ++c) v[c] = 0.f;
#pragma unroll
  for (int p = 0; p < NPART; ++p) {
    const float* row = &s_part[((size_t)p * B + b) * CO + o];
#pragma unroll
    for (int c = 0; c < CDIM; ++c) v[c] += row[c * 16];
  }
  float ns = 0.f;
#pragma unroll
  for (int c = 0; c < CDIM; ++c) ns += v[c] * v[c];
  float f = (ns / (1.f + ns)) / (sqrtf(ns) + 1e-10f);
#pragma unroll
  for (int c = 0; c < CDIM; ++c) out[(size_t)b * CO + c * 16 + o] = v[c] * f;
}

// ---------------------------------------------------------------------------
// Kernel 5 (k_agr, round-7 proven): y[ik][co] = sum_b xtkb[ik][b]*outT[co][b]
// (partial over this block's 64 b's) via MFMA, then agr[i,c] = (1/B) sum W*y,
// atomicAdd into logits. grid (144 i-tiles of 8, 4 b-splits), block 256.
// ---------------------------------------------------------------------------
__global__ void __launch_bounds__(256) k_agr(const float* __restrict__ W,
                                             const unsigned short* __restrict__ xtkb,
                                             const unsigned short* __restrict__ outT,
                                             float* __restrict__ logits) {
  const int bx = blockIdx.x;
  const int bh = blockIdx.y;
  const int t = threadIdx.x, w = t >> 6, l = t & 63;
  const int lr = l & 15, lq = l >> 4;
  __shared__ float yl[64][161];

  f32x4 acc[10];
#pragma unroll
  for (int nt = 0; nt < 10; ++nt) acc[nt] = (f32x4){0.f, 0.f, 0.f, 0.f};

  const unsigned short* Ap = &xtkb[(size_t)(bx * 64 + w * 16 + lr) * B + bh * 64 + lq * 8];
  const unsigned short* Bp = &outT[(size_t)lr * B + bh * 64 + lq * 8];

#pragma unroll
  for (int kc = 0; kc < 2; ++kc) {
    U8B8 a; a.u = *reinterpret_cast<const ushort8*>(Ap + kc * 32);
#pragma unroll
    for (int nt = 0; nt < 10; ++nt) {
      U8B8 bv; bv.u = *reinterpret_cast<const ushort8*>(Bp + (size_t)nt * 16 * B + kc * 32);
      acc[nt] = __builtin_amdgcn_mfma_f32_16x16x32_bf16(a.h, bv.h, acc[nt], 0, 0, 0);
    }
  }
  // D: rows m = ik = w*16 + lq*4 + j, cols n = co = nt*16 + lr
#pragma unroll
  for (int nt = 0; nt < 10; ++nt)
#pragma unroll
    for (int j = 0; j < 4; ++j)
      yl[w * 16 + lq * 4 + j][nt * 16 + lr] = acc[nt][j];
  __syncthreads();

  if (t < 160) {
    const int ii = t / 20, rem = t % 20, cc = rem >> 1, oh = rem & 1;
    const float* Wp = &W[((size_t)(bx * 8 + ii) * CDIM + cc) * 128 + oh * 64];
    float sum = 0.f;
#pragma unroll
    for (int o = 0; o < 8; ++o) {
      float4 w0 = *(const float4*)(&Wp[o * 8]);
      float4 w1 = *(const float4*)(&Wp[o * 8 + 4]);
      int co = cc * 16 + oh * 8 + o;
      sum += w0.x * yl[ii * 8 + 0][co] + w0.y * yl[ii * 8 + 1][co]
           + w0.z * yl[ii * 8 + 2][co] + w0.w * yl[ii * 8 + 3][co]
           + w1.x * yl[ii * 8 + 4][co] + w1.y * yl[ii * 8 + 5][co]
           + w1.z * yl[ii * 8 + 6][co] + w1.w * yl[ii * 8 + 7][co];
    }
    sum += __shfl_xor(sum, 1);
    if (oh == 0) atomicAdd(&logits[(bx * 8 + ii) * CDIM + cc], sum * (1.f / (float)B));
  }
}

// ---------------------------------------------------------------------------
extern "C" void kernel_launch(void* const* d_in, const int* in_sizes, int n_in,
                              void* d_out, int out_size, void* d_ws, size_t ws_size,
                              hipStream_t stream) {
  const float* x = (const float*)d_in[0];       // [B,K,I] f32
  const float* W = (const float*)d_in[1];       // [I,C,O,K] f32
  float* out = (float*)d_out;                   // [B,C,O,1] f32

  float* logits = (float*)d_ws;                              // I*C f32
  float* s_part = logits + IDIM * CDIM;                      // NPART*B*CO f32
  unsigned short* xtbT = (unsigned short*)(s_part + (size_t)NPART * B * CO); // B*IK
  unsigned short* xtkb = xtbT + (size_t)B * IK;              // IK*B
  unsigned short* Wrb  = xtkb + (size_t)IK * B;              // CO*IK
  unsigned short* outT = Wrb + (size_t)CO * IK;              // CO*B

  k_prep<<<360, 256, 0, stream>>>(x, W, xtbT, xtkb, Wrb, logits);

  for (int it = 0; it < 3; ++it) {
    k_s<<<dim3(CDIM, 4, NPART), 256, 0, stream>>>(logits, Wrb, xtbT, s_part);
    if (it < 2) {
      k_sqm<<<16, 256, 0, stream>>>(s_part, outT);
      k_agr<<<dim3(144, 4), 256, 0, stream>>>(W, xtkb, outT, logits);
    } else {
      k_sqf<<<16, 256, 0, stream>>>(s_part, out);
    }
  }
}

// Round 14
// 83.932 us; speedup vs baseline: 2.8074x; 1.3201x over previous
//
#include <hip/hip_runtime.h>

#define B 256
#define KDIM 8
#define IDIM 1152
#define CDIM 10
#define CO 160
#define IK 9216        // IDIM*KDIM
#define NPART 6        // split-K partials in k_s (grid 240 <= 256 CUs)
#define AIT 6          // i's per k_agr block (grid 192*4 = 768 = 3/CU exact)

typedef __bf16 bf16x8 __attribute__((ext_vector_type(8)));
typedef unsigned short ushort8 __attribute__((ext_vector_type(8)));
typedef float f32x4 __attribute__((ext_vector_type(4)));

__device__ __forceinline__ unsigned short f2bf(float f) {
  unsigned u = __float_as_uint(f);
  unsigned r = u + 0x7fff + ((u >> 16) & 1);   // RNE
  return (unsigned short)(r >> 16);
}

union U8B8 { ushort8 u; bf16x8 h; };

// ---------------------------------------------------------------------------
// Kernel 1 (prep): role A (blocks 0..287): x -> xtbT bf16 [b][i*8+k] AND
// xtkb bf16 [i*8+k][b]. role B (288..359): W -> Wrb bf16 [c*16+o][i*8+k];
// first 45 role-B blocks zero logits.
// ---------------------------------------------------------------------------
__global__ void __launch_bounds__(256) k_prep(const float* __restrict__ x,
                                              const float* __restrict__ W,
                                              unsigned short* __restrict__ xtbT,
                                              unsigned short* __restrict__ xtkb,
                                              unsigned short* __restrict__ Wrb,
                                              float* __restrict__ logits) {
  __shared__ __align__(16) unsigned char smem[41280];
  const int bid = blockIdx.x;
  const int t = threadIdx.x;
  if (bid < 288) {
    float* tf = (float*)smem;                 // tile[k][bb][ii]: k*1056+bb*33+ii
    const int i0 = (bid % 36) * 32;
    const int b0 = (bid / 36) * 32;
    const int tx = t & 31, ty = t >> 5;       // ty 0..7
#pragma unroll
    for (int r = 0; r < 4; ++r) {
      int b = b0 + ty + r * 8;
#pragma unroll
      for (int k = 0; k < 8; ++k)
        tf[k * 1056 + (ty + r * 8) * 33 + tx] =
            x[((size_t)b * KDIM + k) * IDIM + i0 + tx];
    }
    __syncthreads();
    // xtbT[b][i*8+k]
#pragma unroll
    for (int r = 0; r < 4; ++r) {
      int idx = r * 256 + t;
      int bb = idx >> 5, ii = idx & 31;
      ushort8 v;
#pragma unroll
      for (int k = 0; k < 8; ++k) v[k] = f2bf(tf[k * 1056 + bb * 33 + ii]);
      *reinterpret_cast<ushort8*>(&xtbT[(size_t)(b0 + bb) * IK + (i0 + ii) * 8]) = v;
    }
    // xtkb[(i*8+k)][b]
#pragma unroll
    for (int ii = 0; ii < 32; ++ii)
      xtkb[((size_t)(i0 + ii) * 8 + ty) * B + b0 + tx] =
          f2bf(tf[ty * 1056 + tx * 33 + ii]);
  } else {
    unsigned short* wt = (unsigned short*)smem;  // wt[ii][j], row stride 1288
    const int bz = bid - 288;                    // 0..71
    const int i0 = bz * 16;
#pragma unroll
    for (int ii = 0; ii < 16; ++ii) {
      const float* src = &W[(size_t)(i0 + ii) * 1280];
#pragma unroll
      for (int p = 0; p < 5; ++p) {
        int j = p * 256 + t;
        wt[ii * 1288 + j] = f2bf(src[j]);
      }
    }
    __syncthreads();
#pragma unroll
    for (int p = 0; p < 10; ++p) {
      int idx = p * 256 + t;
      int co = idx >> 4, ii = idx & 15;
      ushort8 v = *reinterpret_cast<const ushort8*>(&wt[ii * 1288 + co * 8]);
      *reinterpret_cast<ushort8*>(&Wrb[(size_t)co * IK + (i0 + ii) * 8]) = v;
    }
    if (bz < 45) logits[bz * 256 + t] = 0.f;
  }
}

// ---------------------------------------------------------------------------
// Kernel 2 (k_s): fused per-class softmax + MFMA split-K.
// grid (10 c, 4 bt4, 6 g) = 240 blocks (single-round wall on 256 CUs).
// 24 wave-splits x 12 chunks = 288 chunks = full K coverage.
// ---------------------------------------------------------------------------
__global__ void __launch_bounds__(256) k_s(const float* __restrict__ logits,
                                           const unsigned short* __restrict__ Wrb,
                                           const unsigned short* __restrict__ xtbT,
                                           float* __restrict__ s_part) {
  const int c = blockIdx.x, bt4 = blockIdx.y, g = blockIdx.z;
  const int t = threadIdx.x, w = t >> 6, l = t & 63;
  const int lr = l & 15, lq = l >> 4;
  const int s = g * 4 + w;                   // 0..23

  __shared__ float cls[IDIM];
  __shared__ float red4[4];
  __shared__ float red[3 * 1088];

  // ---- softmax over i for class c (redundant per block; cheap) ----
  float m = -1e30f;
  for (int i = t; i < IDIM; i += 256) {
    float v = logits[i * CDIM + c];
    cls[i] = v;
    m = fmaxf(m, v);
  }
#pragma unroll
  for (int off = 32; off; off >>= 1) m = fmaxf(m, __shfl_xor(m, off));
  if ((t & 63) == 0) red4[t >> 6] = m;
  __syncthreads();
  m = fmaxf(fmaxf(red4[0], red4[1]), fmaxf(red4[2], red4[3]));
  __syncthreads();
  float ps = 0.f;
  for (int i = t; i < IDIM; i += 256) {
    float e = expf(cls[i] - m);
    cls[i] = e;
    ps += e;
  }
#pragma unroll
  for (int off = 32; off; off >>= 1) ps += __shfl_xor(ps, off);
  if ((t & 63) == 0) red4[t >> 6] = ps;
  __syncthreads();
  const float rinv = 1.f / (red4[0] + red4[1] + red4[2] + red4[3]);
  for (int i = t; i < IDIM; i += 256) cls[i] *= rinv;
  __syncthreads();

  // ---- MFMA main loop: 12 chunks per wave-split ----
  f32x4 acc[4];
#pragma unroll
  for (int j = 0; j < 4; ++j) acc[j] = (f32x4){0.f, 0.f, 0.f, 0.f};

  const unsigned short* Ap  = &Wrb[((size_t)c * 16 + lr) * IK + lq * 8];
  const unsigned short* Bp0 = &xtbT[((size_t)(bt4 * 64 +  0 + lr)) * IK + lq * 8];
  const unsigned short* Bp1 = &xtbT[((size_t)(bt4 * 64 + 16 + lr)) * IK + lq * 8];
  const unsigned short* Bp2 = &xtbT[((size_t)(bt4 * 64 + 32 + lr)) * IK + lq * 8];
  const unsigned short* Bp3 = &xtbT[((size_t)(bt4 * 64 + 48 + lr)) * IK + lq * 8];

#pragma unroll 4
  for (int t9 = 0; t9 < 12; ++t9) {
    const int kc = s * 12 + t9;
    const int off = kc * 32;
    ushort8 av = *reinterpret_cast<const ushort8*>(Ap + off);
    float qv = cls[kc * 4 + lq];
    U8B8 b0; b0.u = *reinterpret_cast<const ushort8*>(Bp0 + off);
    U8B8 b1; b1.u = *reinterpret_cast<const ushort8*>(Bp1 + off);
    U8B8 b2; b2.u = *reinterpret_cast<const ushort8*>(Bp2 + off);
    U8B8 b3; b3.u = *reinterpret_cast<const ushort8*>(Bp3 + off);
    U8B8 a;
#pragma unroll
    for (int e = 0; e < 8; ++e) {
      float f = __uint_as_float((unsigned)av[e] << 16) * qv;
      a.u[e] = f2bf(f);
    }
    acc[0] = __builtin_amdgcn_mfma_f32_16x16x32_bf16(a.h, b0.h, acc[0], 0, 0, 0);
    acc[1] = __builtin_amdgcn_mfma_f32_16x16x32_bf16(a.h, b1.h, acc[1], 0, 0, 0);
    acc[2] = __builtin_amdgcn_mfma_f32_16x16x32_bf16(a.h, b2.h, acc[2], 0, 0, 0);
    acc[3] = __builtin_amdgcn_mfma_f32_16x16x32_bf16(a.h, b3.h, acc[3], 0, 0, 0);
  }

  // ---- cross-wave reduce, store by wave 0 ----
  if (w) {
#pragma unroll
    for (int j = 0; j < 4; ++j)
#pragma unroll
      for (int j2 = 0; j2 < 4; ++j2)
        red[(w - 1) * 1088 + l * 17 + j * 4 + j2] = acc[j][j2];
  }
  __syncthreads();
  if (w == 0) {
#pragma unroll
    for (int r = 0; r < 3; ++r)
#pragma unroll
      for (int j = 0; j < 4; ++j)
#pragma unroll
        for (int j2 = 0; j2 < 4; ++j2)
          acc[j][j2] += red[r * 1088 + l * 17 + j * 4 + j2];
#pragma unroll
    for (int j = 0; j < 4; ++j)
#pragma unroll
      for (int j2 = 0; j2 < 4; ++j2)
        s_part[((size_t)g * B + bt4 * 64 + j * 16 + lr) * CO + c * 16 + lq * 4 + j2] =
            acc[j][j2];
  }
}

// ---------------------------------------------------------------------------
// Kernel 3 (k_sqm): reduce partials + squash -> outT bf16 [co][b].
// grid 32 blocks x 8 b; COALESCED co-major reads (t = co).
// ---------------------------------------------------------------------------
__global__ void __launch_bounds__(256) k_sqm(const float* __restrict__ s_part,
                                             unsigned short* __restrict__ outT) {
  const int t = threadIdx.x;
  const int b0 = blockIdx.x * 8;
  __shared__ float sq[8][160];
  __shared__ float fo[8][16];
  float vv[8];
  if (t < CO) {
#pragma unroll
    for (int bi = 0; bi < 8; ++bi) {
      float sv = 0.f;
#pragma unroll
      for (int p = 0; p < NPART; ++p)
        sv += s_part[((size_t)p * B + b0 + bi) * CO + t];
      vv[bi] = sv;
      sq[bi][t] = sv * sv;
    }
  }
  __syncthreads();
  if (t < 128) {
    int bi = t >> 4, o = t & 15;
    float ns = 0.f;
#pragma unroll
    for (int c = 0; c < CDIM; ++c) ns += sq[bi][c * 16 + o];
    fo[bi][o] = (ns / (1.f + ns)) / (sqrtf(ns) + 1e-10f);
  }
  __syncthreads();
  if (t < CO) {
    ushort8 v;
#pragma unroll
    for (int bi = 0; bi < 8; ++bi) v[bi] = f2bf(vv[bi] * fo[bi][t & 15]);
    *reinterpret_cast<ushort8*>(&outT[(size_t)t * B + b0]) = v;
  }
}

// ---------------------------------------------------------------------------
// Kernel 4 (k_sqf, last iter): reduce + squash -> d_out f32 [b][c][o].
// grid 32 blocks x 8 b; coalesced.
// ---------------------------------------------------------------------------
__global__ void __launch_bounds__(256) k_sqf(const float* __restrict__ s_part,
                                             float* __restrict__ out) {
  const int t = threadIdx.x;
  const int b0 = blockIdx.x * 8;
  __shared__ float sq[8][160];
  __shared__ float fo[8][16];
  float vv[8];
  if (t < CO) {
#pragma unroll
    for (int bi = 0; bi < 8; ++bi) {
      float sv = 0.f;
#pragma unroll
      for (int p = 0; p < NPART; ++p)
        sv += s_part[((size_t)p * B + b0 + bi) * CO + t];
      vv[bi] = sv;
      sq[bi][t] = sv * sv;
    }
  }
  __syncthreads();
  if (t < 128) {
    int bi = t >> 4, o = t & 15;
    float ns = 0.f;
#pragma unroll
    for (int c = 0; c < CDIM; ++c) ns += sq[bi][c * 16 + o];
    fo[bi][o] = (ns / (1.f + ns)) / (sqrtf(ns) + 1e-10f);
  }
  __syncthreads();
  if (t < CO) {
#pragma unroll
    for (int bi = 0; bi < 8; ++bi)
      out[(size_t)(b0 + bi) * CO + t] = vv[bi] * fo[bi][t & 15];
  }
}

// ---------------------------------------------------------------------------
// Kernel 5 (k_agr): y[ik][co] = sum_b xtkb[ik][b]*outT[co][b] via MFMA
// (partial over 64 b's), yl stored TRANSPOSED [co][ik] (stride 52, 16B-aligned
// rows) so the W-contract reads are float4; then agr -> atomicAdd logits.
// grid (192 bx of 6 i, 4 bh) = 768 = exactly 3 blocks/CU. Waves 0..2 do MFMA
// (48 ik rows = 3 m-tiles); all waves' first 120 threads do the W-contract.
// ---------------------------------------------------------------------------
__global__ void __launch_bounds__(256) k_agr(const float* __restrict__ W,
                                             const unsigned short* __restrict__ xtkb,
                                             const unsigned short* __restrict__ outT,
                                             float* __restrict__ logits) {
  const int bx = blockIdx.x;                 // i0 = bx*6, ik0 = bx*48
  const int bh = blockIdx.y;                 // b0 = bh*64
  const int t = threadIdx.x, w = t >> 6, l = t & 63;
  const int lr = l & 15, lq = l >> 4;
  __shared__ __align__(16) float yl[CO][52];   // [co][ik], 52*4B rows (16B mult)

  if (w < 3) {
    f32x4 acc[10];
#pragma unroll
    for (int nt = 0; nt < 10; ++nt) acc[nt] = (f32x4){0.f, 0.f, 0.f, 0.f};
    const unsigned short* Ap =
        &xtkb[(size_t)(bx * 48 + w * 16 + lr) * B + bh * 64 + lq * 8];
    const unsigned short* Bp = &outT[(size_t)lr * B + bh * 64 + lq * 8];
#pragma unroll
    for (int kc = 0; kc < 2; ++kc) {
      U8B8 a; a.u = *reinterpret_cast<const ushort8*>(Ap + kc * 32);
#pragma unroll
      for (int nt = 0; nt < 10; ++nt) {
        U8B8 bv;
        bv.u = *reinterpret_cast<const ushort8*>(Bp + (size_t)nt * 16 * B + kc * 32);
        acc[nt] = __builtin_amdgcn_mfma_f32_16x16x32_bf16(a.h, bv.h, acc[nt], 0, 0, 0);
      }
    }
    // D rows m = ik = w*16+lq*4+j, cols n = co = nt*16+lr -> yl[co][ik]
#pragma unroll
    for (int nt = 0; nt < 10; ++nt)
#pragma unroll
      for (int j = 0; j < 4; ++j)
        yl[nt * 16 + lr][w * 16 + lq * 4 + j] = acc[nt][j];
  }
  __syncthreads();

  if (t < 120) {                             // 6 i x 10 c x 2 oh
    const int ii = t / 20, rem = t % 20, cc = rem >> 1, oh = rem & 1;
    const float* Wp = &W[((size_t)(bx * AIT + ii) * CDIM + cc) * 128 + oh * 64];
    float sum = 0.f;
#pragma unroll
    for (int o = 0; o < 8; ++o) {
      float4 w0 = *(const float4*)(&Wp[o * 8]);
      float4 w1 = *(const float4*)(&Wp[o * 8 + 4]);
      const float* yr = &yl[cc * 16 + oh * 8 + o][ii * 8];
      float4 y0 = *(const float4*)(&yr[0]);
      float4 y1 = *(const float4*)(&yr[4]);
      sum += w0.x * y0.x + w0.y * y0.y + w0.z * y0.z + w0.w * y0.w
           + w1.x * y1.x + w1.y * y1.y + w1.z * y1.z + w1.w * y1.w;
    }
    sum += __shfl_xor(sum, 1);
    if (oh == 0)
      atomicAdd(&logits[(bx * AIT + ii) * CDIM + cc], sum * (1.f / (float)B));
  }
}

// ---------------------------------------------------------------------------
extern "C" void kernel_launch(void* const* d_in, const int* in_sizes, int n_in,
                              void* d_out, int out_size, void* d_ws, size_t ws_size,
                              hipStream_t stream) {
  const float* x = (const float*)d_in[0];       // [B,K,I] f32
  const float* W = (const float*)d_in[1];       // [I,C,O,K] f32
  float* out = (float*)d_out;                   // [B,C,O,1] f32

  float* logits = (float*)d_ws;                              // I*C f32
  float* s_part = logits + IDIM * CDIM;                      // NPART*B*CO f32
  unsigned short* xtbT = (unsigned short*)(s_part + (size_t)NPART * B * CO);
  unsigned short* xtkb = xtbT + (size_t)B * IK;              // IK*B
  unsigned short* Wrb  = xtkb + (size_t)IK * B;              // CO*IK
  unsigned short* outT = Wrb + (size_t)CO * IK;              // CO*B

  k_prep<<<360, 256, 0, stream>>>(x, W, xtbT, xtkb, Wrb, logits);

  for (int it = 0; it < 3; ++it) {
    k_s<<<dim3(CDIM, 4, NPART), 256, 0, stream>>>(logits, Wrb, xtbT, s_part);
    if (it < 2) {
      k_sqm<<<32, 256, 0, stream>>>(s_part, outT);
      k_agr<<<dim3(IDIM / AIT, 4), 256, 0, stream>>>(W, xtkb, outT, logits);
    } else {
      k_sqf<<<32, 256, 0, stream>>>(s_part, out);
    }
  }
}

// Round 15
// 68.283 us; speedup vs baseline: 3.4508x; 1.2292x over previous
//
#include <hip/hip_runtime.h>

#define B 256
#define KDIM 8
#define IDIM 1152
#define CDIM 10
#define CO 160
#define IK 9216        // IDIM*KDIM
#define NPART 6        // split-K partials in k_s (grid 240 <= 256 CUs)
#define AIT 6          // i's per k_agr block (grid 192*4 = 768 = 3/CU exact)

typedef __bf16 bf16x8 __attribute__((ext_vector_type(8)));
typedef unsigned short ushort8 __attribute__((ext_vector_type(8)));
typedef float f32x4 __attribute__((ext_vector_type(4)));

__device__ __forceinline__ unsigned short f2bf(float f) {
  unsigned u = __float_as_uint(f);
  unsigned r = u + 0x7fff + ((u >> 16) & 1);   // RNE
  return (unsigned short)(r >> 16);
}

union U8B8 { ushort8 u; bf16x8 h; };

// Fragment-order layouts (lane l = lq*16+lr reads base + l*16B, fully
// coalesced 1KB wave transactions):
//   WqP[c][kc][lq][lr][e]       = bf16(W[i=kc*4+lq][c][o=lr][k=e])
//   XbP[bt][kc][lq][lr][e]      = bf16(x[b=bt*16+lr][k=e][i=kc*4+lq])
//   XkP[bx][w][bh][kc][lq][lr][e]= bf16(x[b=bh*64+kc*32+lq*8+e][k=lr&7][i=bx*6+w*2+(lr>>3)])
//   outP[bh][nt][kc][lq][lr][e] = bf16(out[b=bh*64+kc*32+lq*8+e][co=nt*16+lr])

// ---------------------------------------------------------------------------
// Kernel 1 (prep): role A (0..287): x-tile -> XbP + XkP. role B (288..359):
// W -> WqP (direct, no LDS); first 45 role-B blocks zero logits.
// ---------------------------------------------------------------------------
__global__ void __launch_bounds__(256) k_prep(const float* __restrict__ x,
                                              const float* __restrict__ W,
                                              unsigned short* __restrict__ XbP,
                                              unsigned short* __restrict__ XkP,
                                              unsigned short* __restrict__ WqP,
                                              float* __restrict__ logits) {
  const int bid = blockIdx.x;
  const int t = threadIdx.x;
  if (bid < 288) {
    __shared__ float tf[KDIM * 1056];         // tile[k][bb][ii]: k*1056+bb*33+ii
    const int i0 = (bid % 36) * 32;
    const int b0 = (bid / 36) * 32;
    const int tx = t & 31, ty = t >> 5;       // ty 0..7
#pragma unroll
    for (int r = 0; r < 4; ++r) {
      int b = b0 + ty + r * 8;
#pragma unroll
      for (int k = 0; k < 8; ++k)
        tf[k * 1056 + (ty + r * 8) * 33 + tx] =
            x[((size_t)b * KDIM + k) * IDIM + i0 + tx];
    }
    __syncthreads();
    // ---- XbP: idx -> (bth, kc8, lq, lr) ----
#pragma unroll
    for (int r = 0; r < 4; ++r) {
      int idx = r * 256 + t;
      int bth = idx >> 9, kc8 = (idx >> 6) & 7, lq = (idx >> 4) & 3, lr = idx & 15;
      ushort8 v;
#pragma unroll
      for (int e = 0; e < 8; ++e)
        v[e] = f2bf(tf[e * 1056 + (bth * 16 + lr) * 33 + kc8 * 4 + lq]);
      int bt = (b0 >> 4) + bth;
      int kc = (i0 >> 2) + kc8;
      *reinterpret_cast<ushort8*>(
          &XbP[(((size_t)bt * 288 + kc) * 64 + lq * 16 + lr) * 8]) = v;
    }
    // ---- XkP: idx -> (il, k, lql) ----
    {
      const int bh = b0 >> 6, kc = (b0 >> 5) & 1;
#pragma unroll
      for (int r = 0; r < 4; ++r) {
        int idx = r * 256 + t;
        int il = idx >> 5, k = (idx >> 2) & 7, lql = idx & 3;
        int i = i0 + il;
        int bx = i / 6, r6 = i - bx * 6;
        int w = r6 >> 1, lr = (r6 & 1) * 8 + k;
        ushort8 v;
#pragma unroll
        for (int e = 0; e < 8; ++e)
          v[e] = f2bf(tf[k * 1056 + (lql * 8 + e) * 33 + il]);
        *reinterpret_cast<ushort8*>(
            &XkP[((((size_t)(bx * 3 + w) * 4 + bh) * 2 + kc) * 64 + lql * 16 + lr) * 8]) = v;
      }
    }
  } else {
    const int bz = bid - 288;                  // 0..71
    const int i0 = bz * 16;
    const int ii = t >> 4, lr = t & 15;
    const int i = i0 + ii;
    const int kc = i >> 2, lq = i & 3;
#pragma unroll
    for (int c = 0; c < CDIM; ++c) {
      const float* src = &W[(size_t)i * 1280 + c * 128 + lr * 8];
      float4 w0 = *(const float4*)src;
      float4 w1 = *(const float4*)(src + 4);
      ushort8 v;
      v[0] = f2bf(w0.x); v[1] = f2bf(w0.y); v[2] = f2bf(w0.z); v[3] = f2bf(w0.w);
      v[4] = f2bf(w1.x); v[5] = f2bf(w1.y); v[6] = f2bf(w1.z); v[7] = f2bf(w1.w);
      *reinterpret_cast<ushort8*>(
          &WqP[(((size_t)c * 288 + kc) * 64 + lq * 16 + lr) * 8]) = v;
    }
    if (bz < 45) logits[bz * 256 + t] = 0.f;
  }
}

// ---------------------------------------------------------------------------
// Kernel 2 (k_s): MFMA split-K, coalesced fragment loads; softmax fused
// (skipped entirely for iteration 0 via UNI: q == 1/1152 exactly).
// grid (10 c, 4 bt4, 6 g) = 240 blocks; wave-split s = g*4+w, 12 chunks.
// ---------------------------------------------------------------------------
template <bool UNI>
__global__ void __launch_bounds__(256) k_s(const float* __restrict__ logits,
                                           const unsigned short* __restrict__ WqP,
                                           const unsigned short* __restrict__ XbP,
                                           float* __restrict__ s_part) {
  const int c = blockIdx.x, bt4 = blockIdx.y, g = blockIdx.z;
  const int t = threadIdx.x, w = t >> 6, l = t & 63;
  const int lr = l & 15, lq = l >> 4;
  const int s = g * 4 + w;                   // 0..23

  __shared__ float red[3 * 1088];

  float qreg[12];
  if constexpr (UNI) {
#pragma unroll
    for (int t9 = 0; t9 < 12; ++t9) qreg[t9] = 1.f / (float)IDIM;
  } else {
    __shared__ float cls[IDIM];
    __shared__ float red4[4];
    float m = -1e30f;
    for (int i = t; i < IDIM; i += 256) {
      float v = logits[i * CDIM + c];
      cls[i] = v;
      m = fmaxf(m, v);
    }
#pragma unroll
    for (int off = 32; off; off >>= 1) m = fmaxf(m, __shfl_xor(m, off));
    if ((t & 63) == 0) red4[t >> 6] = m;
    __syncthreads();
    m = fmaxf(fmaxf(red4[0], red4[1]), fmaxf(red4[2], red4[3]));
    __syncthreads();
    float ps = 0.f;
    for (int i = t; i < IDIM; i += 256) {
      float e = expf(cls[i] - m);
      cls[i] = e;
      ps += e;
    }
#pragma unroll
    for (int off = 32; off; off >>= 1) ps += __shfl_xor(ps, off);
    if ((t & 63) == 0) red4[t >> 6] = ps;
    __syncthreads();
    const float rinv = 1.f / (red4[0] + red4[1] + red4[2] + red4[3]);
#pragma unroll
    for (int t9 = 0; t9 < 12; ++t9)
      qreg[t9] = cls[(s * 12 + t9) * 4 + lq] * rinv;
  }

  // ---- MFMA main loop: 12 chunks, all loads lane-coalesced ----
  f32x4 acc[4];
#pragma unroll
  for (int j = 0; j < 4; ++j) acc[j] = (f32x4){0.f, 0.f, 0.f, 0.f};

  const unsigned short* Ap  = &WqP[(size_t)c * 147456 + l * 8];
  const unsigned short* Bp0 = &XbP[(size_t)(bt4 * 4 + 0) * 147456 + l * 8];
  const unsigned short* Bp1 = &XbP[(size_t)(bt4 * 4 + 1) * 147456 + l * 8];
  const unsigned short* Bp2 = &XbP[(size_t)(bt4 * 4 + 2) * 147456 + l * 8];
  const unsigned short* Bp3 = &XbP[(size_t)(bt4 * 4 + 3) * 147456 + l * 8];

#pragma unroll 4
  for (int t9 = 0; t9 < 12; ++t9) {
    const int off = (s * 12 + t9) * 512;
    ushort8 av = *reinterpret_cast<const ushort8*>(Ap + off);
    U8B8 b0; b0.u = *reinterpret_cast<const ushort8*>(Bp0 + off);
    U8B8 b1; b1.u = *reinterpret_cast<const ushort8*>(Bp1 + off);
    U8B8 b2; b2.u = *reinterpret_cast<const ushort8*>(Bp2 + off);
    U8B8 b3; b3.u = *reinterpret_cast<const ushort8*>(Bp3 + off);
    U8B8 a;
#pragma unroll
    for (int e = 0; e < 8; ++e) {
      float f = __uint_as_float((unsigned)av[e] << 16) * qreg[t9];
      a.u[e] = f2bf(f);
    }
    acc[0] = __builtin_amdgcn_mfma_f32_16x16x32_bf16(a.h, b0.h, acc[0], 0, 0, 0);
    acc[1] = __builtin_amdgcn_mfma_f32_16x16x32_bf16(a.h, b1.h, acc[1], 0, 0, 0);
    acc[2] = __builtin_amdgcn_mfma_f32_16x16x32_bf16(a.h, b2.h, acc[2], 0, 0, 0);
    acc[3] = __builtin_amdgcn_mfma_f32_16x16x32_bf16(a.h, b3.h, acc[3], 0, 0, 0);
  }

  // ---- cross-wave reduce, store by wave 0 ----
  if (w) {
#pragma unroll
    for (int j = 0; j < 4; ++j)
#pragma unroll
      for (int j2 = 0; j2 < 4; ++j2)
        red[(w - 1) * 1088 + l * 17 + j * 4 + j2] = acc[j][j2];
  }
  __syncthreads();
  if (w == 0) {
#pragma unroll
    for (int r = 0; r < 3; ++r)
#pragma unroll
      for (int j = 0; j < 4; ++j)
#pragma unroll
        for (int j2 = 0; j2 < 4; ++j2)
          acc[j][j2] += red[r * 1088 + l * 17 + j * 4 + j2];
#pragma unroll
    for (int j = 0; j < 4; ++j)
#pragma unroll
      for (int j2 = 0; j2 < 4; ++j2)
        s_part[((size_t)g * B + bt4 * 64 + j * 16 + lr) * CO + c * 16 + lq * 4 + j2] =
            acc[j][j2];
  }
}

// ---------------------------------------------------------------------------
// Kernel 3 (k_sqm): reduce partials + squash -> outP (fragment order).
// grid 32 blocks x 8 b; coalesced co-major reads.
// ---------------------------------------------------------------------------
__global__ void __launch_bounds__(256) k_sqm(const float* __restrict__ s_part,
                                             unsigned short* __restrict__ outP) {
  const int t = threadIdx.x;
  const int b0 = blockIdx.x * 8;
  __shared__ float sq[8][160];
  __shared__ float fo[8][16];
  float vv[8];
  if (t < CO) {
#pragma unroll
    for (int bi = 0; bi < 8; ++bi) {
      float sv = 0.f;
#pragma unroll
      for (int p = 0; p < NPART; ++p)
        sv += s_part[((size_t)p * B + b0 + bi) * CO + t];
      vv[bi] = sv;
      sq[bi][t] = sv * sv;
    }
  }
  __syncthreads();
  if (t < 128) {
    int bi = t >> 4, o = t & 15;
    float ns = 0.f;
#pragma unroll
    for (int c = 0; c < CDIM; ++c) ns += sq[bi][c * 16 + o];
    fo[bi][o] = (ns / (1.f + ns)) / (sqrtf(ns) + 1e-10f);
  }
  __syncthreads();
  if (t < CO) {
    const int nt = t >> 4, lr = t & 15;
    const int bh = b0 >> 6, kc = (b0 >> 5) & 1, lq = (b0 >> 3) & 3;
    ushort8 v;
#pragma unroll
    for (int bi = 0; bi < 8; ++bi) v[bi] = f2bf(vv[bi] * fo[bi][t & 15]);
    *reinterpret_cast<ushort8*>(
        &outP[((((size_t)bh * 10 + nt) * 2 + kc) * 4 + lq) * 128 + lr * 8]) = v;
  }
}

// ---------------------------------------------------------------------------
// Kernel 4 (k_sqf, last iter): reduce + squash -> d_out f32 [b][c][o].
// ---------------------------------------------------------------------------
__global__ void __launch_bounds__(256) k_sqf(const float* __restrict__ s_part,
                                             float* __restrict__ out) {
  const int t = threadIdx.x;
  const int b0 = blockIdx.x * 8;
  __shared__ float sq[8][160];
  __shared__ float fo[8][16];
  float vv[8];
  if (t < CO) {
#pragma unroll
    for (int bi = 0; bi < 8; ++bi) {
      float sv = 0.f;
#pragma unroll
      for (int p = 0; p < NPART; ++p)
        sv += s_part[((size_t)p * B + b0 + bi) * CO + t];
      vv[bi] = sv;
      sq[bi][t] = sv * sv;
    }
  }
  __syncthreads();
  if (t < 128) {
    int bi = t >> 4, o = t & 15;
    float ns = 0.f;
#pragma unroll
    for (int c = 0; c < CDIM; ++c) ns += sq[bi][c * 16 + o];
    fo[bi][o] = (ns / (1.f + ns)) / (sqrtf(ns) + 1e-10f);
  }
  __syncthreads();
  if (t < CO) {
#pragma unroll
    for (int bi = 0; bi < 8; ++bi)
      out[(size_t)(b0 + bi) * CO + t] = vv[bi] * fo[bi][t & 15];
  }
}

// ---------------------------------------------------------------------------
// Kernel 5 (k_agr): y = x*out^T via MFMA (coalesced XkP/outP), yl transposed
// [co][ik] for float4 W-contract, atomicAdd logits.
// grid (192, 4) = 768 = exactly 3 blocks/CU.
// ---------------------------------------------------------------------------
__global__ void __launch_bounds__(256) k_agr(const float* __restrict__ W,
                                             const unsigned short* __restrict__ XkP,
                                             const unsigned short* __restrict__ outP,
                                             float* __restrict__ logits) {
  const int bx = blockIdx.x;                 // i0 = bx*6, ik0 = bx*48
  const int bh = blockIdx.y;                 // b0 = bh*64
  const int t = threadIdx.x, w = t >> 6, l = t & 63;
  const int lr = l & 15, lq = l >> 4;
  __shared__ __align__(16) float yl[CO][52];   // [co][ik]

  if (w < 3) {
    f32x4 acc[10];
#pragma unroll
    for (int nt = 0; nt < 10; ++nt) acc[nt] = (f32x4){0.f, 0.f, 0.f, 0.f};
    const unsigned short* Ap = &XkP[(((size_t)(bx * 3 + w) * 4 + bh) * 1024) + l * 8];
    const unsigned short* Bp = &outP[(size_t)bh * 10240 + l * 8];
#pragma unroll
    for (int kc = 0; kc < 2; ++kc) {
      U8B8 a; a.u = *reinterpret_cast<const ushort8*>(Ap + kc * 512);
#pragma unroll
      for (int nt = 0; nt < 10; ++nt) {
        U8B8 bv;
        bv.u = *reinterpret_cast<const ushort8*>(Bp + nt * 1024 + kc * 512);
        acc[nt] = __builtin_amdgcn_mfma_f32_16x16x32_bf16(a.h, bv.h, acc[nt], 0, 0, 0);
      }
    }
#pragma unroll
    for (int nt = 0; nt < 10; ++nt)
#pragma unroll
      for (int j = 0; j < 4; ++j)
        yl[nt * 16 + lr][w * 16 + lq * 4 + j] = acc[nt][j];
  }
  __syncthreads();

  if (t < 120) {                             // 6 i x 10 c x 2 oh
    const int ii = t / 20, rem = t % 20, cc = rem >> 1, oh = rem & 1;
    const float* Wp = &W[((size_t)(bx * AIT + ii) * CDIM + cc) * 128 + oh * 64];
    float sum = 0.f;
#pragma unroll
    for (int o = 0; o < 8; ++o) {
      float4 w0 = *(const float4*)(&Wp[o * 8]);
      float4 w1 = *(const float4*)(&Wp[o * 8 + 4]);
      const float* yr = &yl[cc * 16 + oh * 8 + o][ii * 8];
      float4 y0 = *(const float4*)(&yr[0]);
      float4 y1 = *(const float4*)(&yr[4]);
      sum += w0.x * y0.x + w0.y * y0.y + w0.z * y0.z + w0.w * y0.w
           + w1.x * y1.x + w1.y * y1.y + w1.z * y1.z + w1.w * y1.w;
    }
    sum += __shfl_xor(sum, 1);
    if (oh == 0)
      atomicAdd(&logits[(bx * AIT + ii) * CDIM + cc], sum * (1.f / (float)B));
  }
}

// ---------------------------------------------------------------------------
extern "C" void kernel_launch(void* const* d_in, const int* in_sizes, int n_in,
                              void* d_out, int out_size, void* d_ws, size_t ws_size,
                              hipStream_t stream) {
  const float* x = (const float*)d_in[0];       // [B,K,I] f32
  const float* W = (const float*)d_in[1];       // [I,C,O,K] f32
  float* out = (float*)d_out;                   // [B,C,O,1] f32

  float* logits = (float*)d_ws;                              // I*C f32
  float* s_part = logits + IDIM * CDIM;                      // NPART*B*CO f32
  unsigned short* XbP = (unsigned short*)(s_part + (size_t)NPART * B * CO);
  unsigned short* XkP = XbP + (size_t)B * IK;                // IK*B
  unsigned short* WqP = XkP + (size_t)IK * B;                // CO*IK
  unsigned short* outP = WqP + (size_t)CO * IK;              // CO*B

  k_prep<<<360, 256, 0, stream>>>(x, W, XbP, XkP, WqP, logits);

  for (int it = 0; it < 3; ++it) {
    if (it == 0)
      k_s<true><<<dim3(CDIM, 4, NPART), 256, 0, stream>>>(logits, WqP, XbP, s_part);
    else
      k_s<false><<<dim3(CDIM, 4, NPART), 256, 0, stream>>>(logits, WqP, XbP, s_part);
    if (it < 2) {
      k_sqm<<<32, 256, 0, stream>>>(s_part, outP);
      k_agr<<<dim3(IDIM / AIT, 4), 256, 0, stream>>>(W, XkP, outP, logits);
    } else {
      k_sqf<<<32, 256, 0, stream>>>(s_part, out);
    }
  }
}